// Round 5
// baseline (889.639 us; speedup 1.0000x reference)
//
#include <hip/hip_runtime.h>
#include <hip/hip_bf16.h>
#include <cstdint>

#define DM 2048
#define DF 8192

typedef int v4i __attribute__((ext_vector_type(4)));
typedef int v16i __attribute__((ext_vector_type(16)));
typedef short v8s __attribute__((ext_vector_type(8)));

__device__ __forceinline__ float silu_f(float y) {
  return y * (1.0f / (1.0f + expf(-y)));
}

__device__ __forceinline__ void gload_lds16(const void* g, void* l) {
  __builtin_amdgcn_global_load_lds(
      (const __attribute__((address_space(1))) void*)g,
      (__attribute__((address_space(3))) void*)l, 16, 0, 0);
}

// ---- stage 1: sum |w| partials ----
__global__ __launch_bounds__(256) void abs_sum_k(const float* __restrict__ w,
                                                 float* __restrict__ partial) {
  const int t = threadIdx.x;
  const float4* wp = (const float4*)w;
  const long base = (long)blockIdx.x * 4096;
  float s = 0.f;
#pragma unroll
  for (int i = 0; i < 16; ++i) {
    float4 v = wp[base + i * 256 + t];
    s += fabsf(v.x) + fabsf(v.y) + fabsf(v.z) + fabsf(v.w);
  }
#pragma unroll
  for (int d = 1; d < 64; d <<= 1) s += __shfl_xor(s, d, 64);
  __shared__ float wsum[4];
  if ((t & 63) == 0) wsum[t >> 6] = s;
  __syncthreads();
  if (t == 0) partial[blockIdx.x] = (wsum[0] + wsum[1]) + (wsum[2] + wsum[3]);
}

// ---- stage 2: finalize weight scales ----
__global__ __launch_bounds__(256) void finalize_scales_k(const float* __restrict__ p1,
                                                         const float* __restrict__ p2,
                                                         float* __restrict__ sc) {
  const float* p = (blockIdx.x == 0) ? p1 : p2;
  const int t = threadIdx.x;
  float s = (p[t] + p[t + 256]) + (p[t + 512] + p[t + 768]);
#pragma unroll
  for (int d = 1; d < 64; d <<= 1) s += __shfl_xor(s, d, 64);
  __shared__ float wsum[4];
  if ((t & 63) == 0) wsum[t >> 6] = s;
  __syncthreads();
  if (t == 0) {
    float total = (wsum[0] + wsum[1]) + (wsum[2] + wsum[3]);
    float mean = total * (1.0f / 16777216.0f);
    float c = fmaxf(mean, 1e-5f);
    sc[blockIdx.x * 2 + 0] = 1.0f / c;
    sc[blockIdx.x * 2 + 1] = c;
  }
}

// ---- ternary weight quantization ----
__global__ __launch_bounds__(256) void tern_quant_k(const float* __restrict__ w,
                                                    int8_t* __restrict__ wq,
                                                    const float* __restrict__ scp) {
  const float s = scp[0];
  const long i = (long)blockIdx.x * 256 + threadIdx.x;
  float4 v = ((const float4*)w)[i];
  int q0 = (int)rintf(v.x * s); q0 = q0 < -1 ? -1 : (q0 > 1 ? 1 : q0);
  int q1 = (int)rintf(v.y * s); q1 = q1 < -1 ? -1 : (q1 > 1 ? 1 : q1);
  int q2 = (int)rintf(v.z * s); q2 = q2 < -1 ? -1 : (q2 > 1 ? 1 : q2);
  int q3 = (int)rintf(v.w * s); q3 = q3 < -1 ? -1 : (q3 > 1 ? 1 : q3);
  ((int*)wq)[i] = (q0 & 255) | ((q1 & 255) << 8) | ((q2 & 255) << 16) | ((q3 & 255) << 24);
}

// ---- per-token activation quant of x ----
__global__ __launch_bounds__(256) void act_quant_x_k(const float* __restrict__ x,
                                                     int8_t* __restrict__ xq,
                                                     float* __restrict__ inv_sx) {
  const int t = threadIdx.x;
  const long row = blockIdx.x;
  const float4* xr = (const float4*)(x + row * DM);
  float4 v0 = xr[t * 2], v1 = xr[t * 2 + 1];
  float m = fmaxf(fmaxf(fmaxf(fabsf(v0.x), fabsf(v0.y)), fmaxf(fabsf(v0.z), fabsf(v0.w))),
                  fmaxf(fmaxf(fabsf(v1.x), fabsf(v1.y)), fmaxf(fabsf(v1.z), fabsf(v1.w))));
#pragma unroll
  for (int d = 1; d < 64; d <<= 1) m = fmaxf(m, __shfl_xor(m, d, 64));
  __shared__ float wm[4];
  if ((t & 63) == 0) wm[t >> 6] = m;
  __syncthreads();
  m = fmaxf(fmaxf(wm[0], wm[1]), fmaxf(wm[2], wm[3]));
  const float scale = 127.0f / fmaxf(m, 1e-5f);
  if (t == 0) inv_sx[row] = 1.0f / scale;
  float vv[8] = {v0.x, v0.y, v0.z, v0.w, v1.x, v1.y, v1.z, v1.w};
  int q[8];
#pragma unroll
  for (int j = 0; j < 8; ++j) {
    int qq = (int)rintf(vv[j] * scale);
    q[j] = qq < -128 ? -128 : (qq > 127 ? 127 : qq);
  }
  int lo = (q[0] & 255) | ((q[1] & 255) << 8) | ((q[2] & 255) << 16) | ((q[3] & 255) << 24);
  int hi = (q[4] & 255) | ((q[5] & 255) << 8) | ((q[6] & 255) << 16) | ((q[7] & 255) << 24);
  ((int2*)(xq + row * DM))[t] = make_int2(lo, hi);
}

// ---- helpers for the 4-wave GEMM ----
__device__ __forceinline__ void stage_part(const int8_t* s, uint8_t* d, long Kl) {
  gload_lds16(s, d);
  gload_lds16(s + 32 * Kl, d + 4096);
  gload_lds16(s + 64 * Kl, d + 8192);
  gload_lds16(s + 96 * Kl, d + 12288);
}

__device__ __forceinline__ void rd_frags(const uint8_t* sA, const uint8_t* sB,
                                         int rowA, int cks,
                                         v4i (&Af)[4], v4i (&Bf)[4]) {
#pragma unroll
  for (int q = 0; q < 4; ++q) {
    Af[q] = *(const v4i*)(sA + q * 4096 + rowA + cks);
    Bf[q] = *(const v4i*)(sB + q * 4096 + rowA + cks);
  }
}

__device__ __forceinline__ void mfma16(const v4i (&Af)[4], const v4i (&Bf)[4],
                                       v16i (&acc)[4][4]) {
#pragma unroll
  for (int mt = 0; mt < 4; ++mt)
#pragma unroll
    for (int nt = 0; nt < 4; ++nt)
      acc[mt][nt] = __builtin_amdgcn_mfma_i32_32x32x32_i8(Af[mt], Bf[nt], acc[mt][nt], 0, 0, 0);
}

// ---- int8 GEMM, 256x256 tile, BK=128B, 4 waves (2x2), wave-tile 128x128 ----
// mfma_i32_32x32x32_i8, acc = 4x4 v16i = 256 VGPRs/lane (1 wave/SIMD).
// LDS 128KB: 2 dbuf x 4 parts(16KB): [A0|A1|B0|B1]. Full next-tile prefetch into
// the opposite buffer each iteration; ONE __syncthreads per K-tile (drains vmcnt).
// XOR-swizzle (row&7)<<4 via pre-swizzled global source (rule #21).
template <int K, int N, int EPI>
__global__ __launch_bounds__(256, 1) void gemm4_i8_k(
    const int8_t* __restrict__ A, const int8_t* __restrict__ B,
    const float* __restrict__ rowInv, const float* __restrict__ invswp,
    short* __restrict__ Y16, float* __restrict__ rowmaxP,
    float* __restrict__ Out) {
  constexpr int NT = K / 128;
  constexpr int NBX = N / 256;
  constexpr int NSTX = NBX / 4;   // supertile = 8by x 4bx = 32 blocks
  __shared__ __align__(16) uint8_t lds[131072];

  const int t = threadIdx.x;
  const int wave = t >> 6;
  const int lane = t & 63;
  const int wr = wave >> 1, wc = wave & 1;   // 2x2 waves, 128x128 each
  const int l31 = lane & 31, kg = lane >> 5;

  // XCD chunk then 8x4 supertile order within chunk (both grids: cpx % 32 == 0)
  const int cpx = (int)gridDim.x >> 3;
  const int bid0 = blockIdx.x;
  const int bid = (bid0 & 7) * cpx + (bid0 >> 3);
  const int st = bid >> 5, u = bid & 31;
  const int by = (st / NSTX) * 8 + (u >> 2);
  const int bx = (st % NSTX) * 4 + (u & 3);
  const long arow0 = (long)by * 256;
  const long bcol0 = (long)bx * 256;

  // staging: thread t sources global row (part_row + t>>3 + {0,32,64,96}),
  // col pre-swizzled so linear LDS dest ends up XOR-swizzled.
  const int srow8 = t >> 3;
  const int scol = ((t & 7) ^ (srow8 & 7)) << 4;
  const int8_t* src0 = A + (arow0 + srow8) * (long)K + scol;        // A rows 0-127
  const int8_t* src1 = src0 + (long)128 * K;                        // A rows 128-255
  const int8_t* src2 = B + (bcol0 + srow8) * (long)K + scol;        // B rows 0-127
  const int8_t* src3 = src2 + (long)128 * K;                        // B rows 128-255
  uint8_t* dstb = lds + (wave << 10);

  // fragment read constants
  const uint8_t* sAbase = lds + (wr << 14);
  const uint8_t* sBbase = lds + ((2 + wc) << 14);
  const int rowA = l31 * 128;
  const int swz = (l31 & 7) << 4;

  v16i acc[4][4] = {};
  v4i A0[4], B0[4], A1[4], B1[4];

#define STAGE_ALL(kk)                                                      \
  do {                                                                     \
    if ((kk) < NT) {                                                       \
      const long ko = (long)(kk) << 7;                                     \
      uint8_t* db = dstb + (((kk) & 1) << 16);                             \
      stage_part(src0 + ko, db, K);                                        \
      stage_part(src1 + ko, db + 16384, K);                                \
      stage_part(src2 + ko, db + 32768, K);                                \
      stage_part(src3 + ko, db + 49152, K);                                \
    }                                                                      \
  } while (0)

  STAGE_ALL(0);
  __syncthreads();

  for (int kt = 0; kt < NT; ++kt) {
    const uint8_t* sA = sAbase + ((kt & 1) << 16);
    const uint8_t* sB = sBbase + ((kt & 1) << 16);
    rd_frags(sA, sB, rowA, (0 * 32 + kg * 16) ^ swz, A0, B0);
    STAGE_ALL(kt + 1);                       // into opposite buffer, race-free
    rd_frags(sA, sB, rowA, (1 * 32 + kg * 16) ^ swz, A1, B1);
    mfma16(A0, B0, acc);                     // ks0
    rd_frags(sA, sB, rowA, (2 * 32 + kg * 16) ^ swz, A0, B0);
    mfma16(A1, B1, acc);                     // ks1
    rd_frags(sA, sB, rowA, (3 * 32 + kg * 16) ^ swz, A1, B1);
    mfma16(A0, B0, acc);                     // ks2
    mfma16(A1, B1, acc);                     // ks3
    __syncthreads();                         // drains vmcnt+lgkm; buffer flip
  }

  const float invsw = invswp[0];
  if constexpr (EPI == 1) {
    // Phase A: clamp + stage y16 to LDS short[256][256], byte XOR (row&7)<<4
#pragma unroll
    for (int mt = 0; mt < 4; ++mt)
#pragma unroll
      for (int nt = 0; nt < 4; ++nt)
#pragma unroll
        for (int r = 0; r < 16; ++r) {
          const int row = wr * 128 + mt * 32 + (r & 3) + 8 * (r >> 2) + 4 * kg;
          const int col = wc * 128 + nt * 32 + l31;
          int yi = acc[mt][nt][r];
          int ys = yi < -32767 ? -32767 : (yi > 32767 ? 32767 : yi);
          *(short*)(lds + ((row * 512 + col * 2) ^ ((row & 7) << 4))) = (short)ys;
        }
    __syncthreads();
    // Phase B: thread t owns row t: silu-rowmax + coalesced-per-thread stores
    const long grow = arow0 + t;
    const float c1v = rowInv[grow] * invsw;
    float mx = 0.f;
    short* gp = Y16 + grow * (long)DF + bcol0;
#pragma unroll
    for (int i = 0; i < 32; ++i) {
      v8s yv = *(const v8s*)(lds + ((t * 512 + i * 16) ^ ((t & 7) << 4)));
#pragma unroll
      for (int j = 0; j < 8; ++j) mx = fmaxf(mx, fabsf(silu_f((float)yv[j] * c1v)));
      *(v8s*)(gp + i * 8) = yv;
    }
    rowmaxP[grow * NBX + bx] = mx;
  } else {
#pragma unroll
    for (int mt = 0; mt < 4; ++mt)
#pragma unroll
      for (int r = 0; r < 16; ++r) {
        const long grow = arow0 + wr * 128 + mt * 32 + (r & 3) + 8 * (r >> 2) + 4 * kg;
        const float c2 = rowInv[grow] * invsw;
#pragma unroll
        for (int nt = 0; nt < 4; ++nt)
          Out[grow * N + bcol0 + wc * 128 + nt * 32 + l31] = (float)acc[mt][nt][r] * c2;
      }
  }
#undef STAGE_ALL
}

// ---- quantize h per-token from int16 y ----
__global__ __launch_bounds__(256) void quant_h_k(const short* __restrict__ Y16,
                                                 const float* __restrict__ rowmaxP,
                                                 const float* __restrict__ inv_sx,
                                                 const float* __restrict__ sc,
                                                 int8_t* __restrict__ hq,
                                                 float* __restrict__ inv_sh) {
  const int t = threadIdx.x;
  const long row = blockIdx.x;
  __shared__ float smax_s;
  if (t < 64) {
    float m = (t < 32) ? rowmaxP[row * 32 + t] : 0.f;
#pragma unroll
    for (int d = 1; d < 64; d <<= 1) m = fmaxf(m, __shfl_xor(m, d, 64));
    if (t == 0) smax_s = m;
  }
  __syncthreads();
  const float scale = 127.0f / fmaxf(smax_s, 1e-5f);
  if (t == 0) inv_sh[row] = 1.0f / scale;
  const float c1 = inv_sx[row] * sc[1];
  const short4* yp = (const short4*)(Y16 + row * DF);
  int* op = (int*)(hq + row * DF);
#pragma unroll
  for (int b = 0; b < 8; ++b) {
    short4 s4 = yp[b * 256 + t];
    short vals[4] = {s4.x, s4.y, s4.z, s4.w};
    int q[4];
#pragma unroll
    for (int j = 0; j < 4; ++j) {
      float h = silu_f((float)vals[j] * c1);
      int qq = (int)rintf(h * scale);
      q[j] = qq < -128 ? -128 : (qq > 127 ? 127 : qq);
    }
    op[b * 256 + t] = (q[0] & 255) | ((q[1] & 255) << 8) | ((q[2] & 255) << 16) | ((q[3] & 255) << 24);
  }
}

extern "C" void kernel_launch(void* const* d_in, const int* in_sizes, int n_in,
                              void* d_out, int out_size, void* d_ws, size_t ws_size,
                              hipStream_t stream) {
  const float* x = (const float*)d_in[0];
  const float* W1 = (const float*)d_in[1];
  const float* W2 = (const float*)d_in[2];
  float* out = (float*)d_out;

  uint8_t* w = (uint8_t*)d_ws;
  float* sc = (float*)(w + 0);
  float* p1 = (float*)(w + 256);
  float* p2 = (float*)(w + 256 + 4096);
  float* inv_sx = (float*)(w + 8448);
  float* inv_sh = (float*)(w + 8448 + 65536);
  float* rowmaxP = (float*)(w + 8448 + 131072);
  uint8_t* w1q = w + 8448 + 131072 + 4194304;
  uint8_t* w2q = w1q + 16777216;
  uint8_t* xq = w2q + 16777216;
  uint8_t* hq = xq + 33554432;
  short* y16 = (short*)(hq + 134217728);

  abs_sum_k<<<1024, 256, 0, stream>>>(W1, p1);
  abs_sum_k<<<1024, 256, 0, stream>>>(W2, p2);
  finalize_scales_k<<<2, 256, 0, stream>>>(p1, p2, sc);
  tern_quant_k<<<16384, 256, 0, stream>>>(W1, (int8_t*)w1q, sc + 0);
  tern_quant_k<<<16384, 256, 0, stream>>>(W2, (int8_t*)w2q, sc + 2);
  act_quant_x_k<<<16384, 256, 0, stream>>>(x, (int8_t*)xq, inv_sx);
  // GEMM1: [16384,2048] x [8192,2048]^T -> y16 + rowmax partials
  gemm4_i8_k<2048, 8192, 1><<<2048, 256, 0, stream>>>(
      (const int8_t*)xq, (const int8_t*)w1q, inv_sx, sc + 1, y16, rowmaxP, nullptr);
  quant_h_k<<<16384, 256, 0, stream>>>(y16, rowmaxP, inv_sx, sc, (int8_t*)hq, inv_sh);
  // GEMM2: [16384,8192] x [2048,8192]^T -> out
  gemm4_i8_k<8192, 2048, 0><<<512, 256, 0, stream>>>(
      (const int8_t*)hq, (const int8_t*)w2q, inv_sh, sc + 3, nullptr, nullptr, out);
}